// Round 1
// baseline (267.737 us; speedup 1.0000x reference)
//
#include <hip/hip_runtime.h>
#include <hip/hip_bf16.h>
#include <math.h>

#define T_TOK 2048
#define DIM 512
#define HID 1024
#define NE 8

typedef __attribute__((ext_vector_type(8))) short short8;
typedef __attribute__((ext_vector_type(4))) float floatx4;

__device__ inline unsigned short f2bf_bits(float f) {
    __hip_bfloat16 h = __float2bfloat16(f);
    return *reinterpret_cast<unsigned short*>(&h);
}

// ---------------- cast fp32 -> bf16, float4 vectorized ----------------
__global__ void cast_f32_bf16(const float* __restrict__ src,
                              unsigned short* __restrict__ dst, int n4) {
    int i = blockIdx.x * blockDim.x + threadIdx.x;
    if (i >= n4) return;
    float4 v = reinterpret_cast<const float4*>(src)[i];
    ushort4 o;
    o.x = f2bf_bits(v.x);
    o.y = f2bf_bits(v.y);
    o.z = f2bf_bits(v.z);
    o.w = f2bf_bits(v.w);
    reinterpret_cast<ushort4*>(dst)[i] = o;
}

// ---------------- router: wave per token ----------------
__global__ void router_kernel(const float* __restrict__ x,
                              const float* __restrict__ wr,
                              const float* __restrict__ br,
                              float* __restrict__ logits_out,
                              int* __restrict__ counts,
                              int* __restrict__ tlist,
                              float* __restrict__ wlist) {
    int wave = threadIdx.x >> 6;
    int lane = threadIdx.x & 63;
    int t = blockIdx.x * 4 + wave;
    if (t >= T_TOK) return;

    float p[NE];
#pragma unroll
    for (int e = 0; e < NE; e++) p[e] = 0.f;

    const float* xr = x + t * DIM;
    for (int d = lane; d < DIM; d += 64) {
        float xv = xr[d];
#pragma unroll
        for (int e = 0; e < NE; e++) p[e] += xv * wr[e * DIM + d];
    }
#pragma unroll
    for (int e = 0; e < NE; e++) {
#pragma unroll
        for (int off = 32; off >= 1; off >>= 1)
            p[e] += __shfl_xor(p[e], off, 64);
    }
    if (lane == 0) {
        float l[NE];
#pragma unroll
        for (int e = 0; e < NE; e++) {
            l[e] = p[e] + br[e];
            logits_out[t * NE + e] = l[e];
        }
        // top-2, jax tie-break = lowest index first
        int e1 = 0;
#pragma unroll
        for (int e = 1; e < NE; e++) if (l[e] > l[e1]) e1 = e;
        int e2 = -1;
#pragma unroll
        for (int e = 0; e < NE; e++) {
            if (e == e1) continue;
            if (e2 < 0 || l[e] > l[e2]) e2 = e;
        }
        // renormalized top-2 softmax weights
        float z = __expf(l[e2] - l[e1]);
        float inv = 1.f / (1.f + z);
        float p1 = inv, p2 = z * inv;
        int pos1 = atomicAdd(&counts[e1], 1);
        tlist[e1 * T_TOK + pos1] = t;
        wlist[e1 * T_TOK + pos1] = p1;
        int pos2 = atomicAdd(&counts[e2], 1);
        tlist[e2 * T_TOK + pos2] = t;
        wlist[e2 * T_TOK + pos2] = p2;
    }
}

// ---------------- MoE expert GEMM ----------------
// Block: 256 threads = 4 waves. TM=16 tokens per block.
// Per block: y[16, 512] = gelu(Xg[16,512] @ w1[e]^T) @ w2[e]^T, weighted atomicAdd.
// Loop over H in 16 chunks of 64; each wave owns 16 h-cols in GEMM1 and
// 128 d-cols in GEMM2.
__global__ __launch_bounds__(256, 2)
void moe_gemm(const unsigned short* __restrict__ xb,
              const unsigned short* __restrict__ w1b,
              const unsigned short* __restrict__ w2b,
              const int* __restrict__ counts,
              const int* __restrict__ tlist,
              const float* __restrict__ wlist,
              float* __restrict__ out) {
    int bx = blockIdx.x;
    int e = bx & 7;           // expert = bx % 8 -> XCD affinity (blockIdx % 8 = XCD)
    int tile = bx >> 3;
    int cnt = counts[e];
    int base = tile * 16;
    if (base >= cnt) return;

    __shared__ int s_tok[16];
    __shared__ float s_wgt[16];
    __shared__ __align__(16) unsigned short s_h[16][72];  // +8 pad: 2-way-max bank alias

    int tid = threadIdx.x;
    if (tid < 16) {
        int idx = base + tid;
        int ok = (idx < cnt) ? 1 : 0;
        int src = e * T_TOK + (ok ? idx : base);
        s_tok[tid] = tlist[src];
        s_wgt[tid] = ok ? wlist[src] : 0.f;
    }
    __syncthreads();

    int wave = tid >> 6, lane = tid & 63;
    int g = lane >> 4, ln = lane & 15;

    // A-frags for GEMM1: A[m=ln][k = kk*32 + g*8 + j], all K=512 in registers
    const short* xrow = (const short*)xb + s_tok[ln] * DIM + g * 8;
    short8 a1[16];
#pragma unroll
    for (int kk = 0; kk < 16; kk++)
        a1[kk] = *(const short8*)(xrow + kk * 32);

    floatx4 acc[8];
#pragma unroll
    for (int i = 0; i < 8; i++) acc[i] = (floatx4){0.f, 0.f, 0.f, 0.f};

    // B-frag base pointers (lane-resolved)
    const short* w1p = (const short*)w1b + ((e * HID + wave * 16 + ln) * DIM + g * 8);
    const short* w2p = (const short*)w2b + ((e * DIM + wave * 128 + ln) * HID + g * 8);

    for (int c = 0; c < 16; c++) {
        // ---- GEMM1: h[:, c*64 + wave*16 + (0..15)] ----
        floatx4 h_acc = (floatx4){0.f, 0.f, 0.f, 0.f};
        const short* w1c = w1p + c * 64 * DIM;
#pragma unroll
        for (int kk = 0; kk < 16; kk++) {
            short8 b = *(const short8*)(w1c + kk * 32);
            h_acc = __builtin_amdgcn_mfma_f32_16x16x32_bf16(a1[kk], b, h_acc, 0, 0, 0);
        }
        // exact gelu, write bf16 to LDS (C layout: row = g*4+r, col = wave*16+ln)
#pragma unroll
        for (int r = 0; r < 4; r++) {
            float v = h_acc[r];
            float gv = 0.5f * v * (1.f + erff(v * 0.70710678118f));
            s_h[g * 4 + r][wave * 16 + ln] = f2bf_bits(gv);
        }
        __syncthreads();
        // ---- GEMM2: acc[dt] += h[16,64] @ w2[dcols,64]^T ----
        short8 a2[2];
#pragma unroll
        for (int kk = 0; kk < 2; kk++)
            a2[kk] = *(const short8*)((const short*)&s_h[ln][kk * 32 + g * 8]);
        const short* w2c = w2p + c * 64;
#pragma unroll
        for (int dt = 0; dt < 8; dt++) {
            const short* w2t = w2c + dt * 16 * HID;
#pragma unroll
            for (int kk = 0; kk < 2; kk++) {
                short8 b = *(const short8*)(w2t + kk * 32);
                acc[dt] = __builtin_amdgcn_mfma_f32_16x16x32_bf16(a2[kk], b, acc[dt], 0, 0, 0);
            }
        }
        __syncthreads();
    }

    // epilogue: weighted atomic accumulate into out
#pragma unroll
    for (int dt = 0; dt < 8; dt++) {
        int col = wave * 128 + dt * 16 + ln;
#pragma unroll
        for (int r = 0; r < 4; r++) {
            int m = g * 4 + r;
            float val = acc[dt][r] * s_wgt[m];
            atomicAdd(out + s_tok[m] * DIM + col, val);
        }
    }
}

extern "C" void kernel_launch(void* const* d_in, const int* in_sizes, int n_in,
                              void* d_out, int out_size, void* d_ws, size_t ws_size,
                              hipStream_t stream) {
    const float* x  = (const float*)d_in[0];
    const float* wr = (const float*)d_in[1];
    const float* br = (const float*)d_in[2];
    const float* w1 = (const float*)d_in[3];
    const float* w2 = (const float*)d_in[4];
    float* out = (float*)d_out;
    float* logits_out = out + T_TOK * DIM;

    char* ws = (char*)d_ws;
    int*   counts = (int*)(ws + 0);
    int*   tlist  = (int*)(ws + 64);
    float* wlist  = (float*)(ws + 64 + 65536);
    unsigned short* xb  = (unsigned short*)(ws + 131328);            // 2 MB
    unsigned short* w1b = (unsigned short*)(ws + 2228480);           // 8 MB
    unsigned short* w2b = (unsigned short*)(ws + 10617088);          // 8 MB
    // total ws needed ~19 MB

    hipMemsetAsync(counts, 0, 64, stream);
    hipMemsetAsync(out, 0, T_TOK * DIM * sizeof(float), stream);

    cast_f32_bf16<<<4096, 256, 0, stream>>>(w1, w1b, (NE * HID * DIM) / 4);
    cast_f32_bf16<<<4096, 256, 0, stream>>>(w2, w2b, (NE * DIM * HID) / 4);
    cast_f32_bf16<<<1024, 256, 0, stream>>>(x, xb, (T_TOK * DIM) / 4);

    router_kernel<<<T_TOK / 4, 256, 0, stream>>>(x, wr, br, logits_out,
                                                 counts, tlist, wlist);

    moe_gemm<<<NE * (T_TOK / 16), 256, 0, stream>>>(xb, w1b, w2b,
                                                    counts, tlist, wlist, out);
}

// Round 2
// 219.288 us; speedup vs baseline: 1.2209x; 1.2209x over previous
//
#include <hip/hip_runtime.h>
#include <hip/hip_bf16.h>
#include <math.h>

#define T_TOK 2048
#define DIM 512
#define HID 1024
#define NE 8
#define TM 32
#define XPAD 516   // shorts per s_x row: 1032 B -> row shifts 2 banks, 2-way max (free)
#define HPAD 136   // shorts per s_h row: 272 B -> row shifts 4 banks, 2-way max (free)

typedef __attribute__((ext_vector_type(8))) short short8;
typedef __attribute__((ext_vector_type(4))) float floatx4;

__device__ inline unsigned short f2bf_bits(float f) {
    __hip_bfloat16 h = __float2bfloat16(f);
    return *reinterpret_cast<unsigned short*>(&h);
}

// ---------------- fused cast fp32 -> bf16 for w1, w2, x ----------------
__global__ void cast_all(const float* __restrict__ w1, const float* __restrict__ w2,
                         const float* __restrict__ x,
                         unsigned short* __restrict__ w1b, unsigned short* __restrict__ w2b,
                         unsigned short* __restrict__ xb) {
    const int n1 = NE * HID * DIM / 4;           // 1048576 float4
    const int n2 = NE * DIM * HID / 4;           // 1048576
    const int n3 = T_TOK * DIM / 4;              // 262144
    const int total = n1 + n2 + n3;
    for (int i = blockIdx.x * blockDim.x + threadIdx.x; i < total;
         i += gridDim.x * blockDim.x) {
        const float* s; unsigned short* d; int j;
        if (i < n1)            { s = w1; d = w1b; j = i; }
        else if (i < n1 + n2)  { s = w2; d = w2b; j = i - n1; }
        else                   { s = x;  d = xb;  j = i - n1 - n2; }
        float4 v = reinterpret_cast<const float4*>(s)[j];
        ushort4 o;
        o.x = f2bf_bits(v.x); o.y = f2bf_bits(v.y);
        o.z = f2bf_bits(v.z); o.w = f2bf_bits(v.w);
        reinterpret_cast<ushort4*>(d)[j] = o;
    }
}

// ---------------- router: wave per token ----------------
__global__ void router_kernel(const float* __restrict__ x,
                              const float* __restrict__ wr,
                              const float* __restrict__ br,
                              float* __restrict__ logits_out,
                              int* __restrict__ counts,
                              int* __restrict__ tlist,
                              float* __restrict__ wlist) {
    int wave = threadIdx.x >> 6;
    int lane = threadIdx.x & 63;
    int t = blockIdx.x * 4 + wave;
    if (t >= T_TOK) return;

    float p[NE];
#pragma unroll
    for (int e = 0; e < NE; e++) p[e] = 0.f;

    const float* xr = x + t * DIM;
    for (int d = lane; d < DIM; d += 64) {
        float xv = xr[d];
#pragma unroll
        for (int e = 0; e < NE; e++) p[e] += xv * wr[e * DIM + d];
    }
#pragma unroll
    for (int e = 0; e < NE; e++) {
#pragma unroll
        for (int off = 32; off >= 1; off >>= 1)
            p[e] += __shfl_xor(p[e], off, 64);
    }
    if (lane == 0) {
        float l[NE];
#pragma unroll
        for (int e = 0; e < NE; e++) {
            l[e] = p[e] + br[e];
            logits_out[t * NE + e] = l[e];
        }
        int e1 = 0;
#pragma unroll
        for (int e = 1; e < NE; e++) if (l[e] > l[e1]) e1 = e;
        int e2 = -1;
#pragma unroll
        for (int e = 0; e < NE; e++) {
            if (e == e1) continue;
            if (e2 < 0 || l[e] > l[e2]) e2 = e;
        }
        float z = __expf(l[e2] - l[e1]);
        float inv = 1.f / (1.f + z);
        float p1 = inv, p2 = z * inv;
        int pos1 = atomicAdd(&counts[e1], 1);
        tlist[e1 * T_TOK + pos1] = t;
        wlist[e1 * T_TOK + pos1] = p1;
        int pos2 = atomicAdd(&counts[e2], 1);
        tlist[e2 * T_TOK + pos2] = t;
        wlist[e2 * T_TOK + pos2] = p2;
    }
}

// ---------------- MoE expert GEMM ----------------
// Block: 512 threads = 8 waves. TM=32 tokens, H half (512) per block.
// grid = 8 experts * 2 H-halves * 64 tiles; expert = blockIdx%8 -> XCD affinity.
// Per c-chunk (128 h): GEMM1 -> gelu -> LDS -> GEMM2 accumulate y[32,512] partial.
__global__ __launch_bounds__(512, 2)
void moe_gemm(const unsigned short* __restrict__ xb,
              const unsigned short* __restrict__ w1b,
              const unsigned short* __restrict__ w2b,
              const int* __restrict__ counts,
              const int* __restrict__ tlist,
              const float* __restrict__ wlist,
              float* __restrict__ out) {
    int bx = blockIdx.x;
    int e = bx & 7;
    int rest = bx >> 3;
    int hh = rest & 1;        // H half
    int tile = rest >> 1;
    int cnt = counts[e];
    int base = tile * TM;
    if (base >= cnt) return;

    __shared__ int s_tok[TM];
    __shared__ float s_wgt[TM];
    __shared__ __align__(16) unsigned short s_x[TM][XPAD];
    __shared__ __align__(16) unsigned short s_h[TM][HPAD];

    int tid = threadIdx.x;
    if (tid < TM) {
        int idx = base + tid;
        int ok = (idx < cnt) ? 1 : 0;
        int src = e * T_TOK + (ok ? idx : base);
        s_tok[tid] = tlist[src];
        s_wgt[tid] = ok ? wlist[src] : 0.f;
    }
    __syncthreads();

    // stage X tile [32, 512] bf16 into padded LDS
    {
        int row = tid >> 4;          // 0..31
        int c0 = tid & 15;
        const short8* src = reinterpret_cast<const short8*>(
            (const short*)xb + s_tok[row] * DIM);
#pragma unroll
        for (int rep = 0; rep < 4; rep++) {
            int c16 = c0 + rep * 16;
            *reinterpret_cast<short8*>(&s_x[row][c16 * 8]) = src[c16];
        }
    }
    __syncthreads();

    int wave = tid >> 6, lane = tid & 63;
    int g = lane >> 4, ln = lane & 15;

    floatx4 acc2[2][4];
#pragma unroll
    for (int mt = 0; mt < 2; mt++)
#pragma unroll
        for (int nt = 0; nt < 4; nt++)
            acc2[mt][nt] = (floatx4){0.f, 0.f, 0.f, 0.f};

    // lane-resolved weight base pointers
    const short* w1base = (const short*)w1b +
        ((e * HID + hh * 512 + wave * 16 + ln) * DIM) + g * 8;
    const short* w2base = (const short*)w2b +
        ((e * DIM + wave * 64 + ln) * HID) + hh * 512 + g * 8;

    for (int c = 0; c < 4; c++) {
        // ---- GEMM1: h[:, chunk] for 128 h-cols; wave owns 16 cols, 2 m-tiles
        floatx4 h1[2];
        h1[0] = (floatx4){0.f, 0.f, 0.f, 0.f};
        h1[1] = (floatx4){0.f, 0.f, 0.f, 0.f};
        const short* w1p = w1base + c * 128 * DIM;
#pragma unroll
        for (int ks = 0; ks < 16; ks++) {
            short8 b  = *reinterpret_cast<const short8*>(w1p + ks * 32);
            short8 a0 = *reinterpret_cast<const short8*>(&s_x[ln][ks * 32 + g * 8]);
            short8 a1 = *reinterpret_cast<const short8*>(&s_x[16 + ln][ks * 32 + g * 8]);
            h1[0] = __builtin_amdgcn_mfma_f32_16x16x32_bf16(a0, b, h1[0], 0, 0, 0);
            h1[1] = __builtin_amdgcn_mfma_f32_16x16x32_bf16(a1, b, h1[1], 0, 0, 0);
        }
        // exact gelu -> bf16 -> LDS (C layout: row = g*4+r, col = wave*16+ln)
#pragma unroll
        for (int mt = 0; mt < 2; mt++)
#pragma unroll
            for (int r = 0; r < 4; r++) {
                float v = h1[mt][r];
                float gv = 0.5f * v * (1.f + erff(v * 0.70710678118f));
                s_h[mt * 16 + g * 4 + r][wave * 16 + ln] = f2bf_bits(gv);
            }
        __syncthreads();

        // ---- GEMM2: y[32, 512] += h[32,128] @ w2[:, chunk]^T; wave owns 64 d-cols
        short8 a2[2][4];
#pragma unroll
        for (int mt = 0; mt < 2; mt++)
#pragma unroll
            for (int kk = 0; kk < 4; kk++)
                a2[mt][kk] = *reinterpret_cast<const short8*>(
                    &s_h[mt * 16 + ln][kk * 32 + g * 8]);
        const short* w2p = w2base + c * 128;
#pragma unroll
        for (int nt = 0; nt < 4; nt++) {
            const short* w2n = w2p + nt * 16 * HID;
#pragma unroll
            for (int kk = 0; kk < 4; kk++) {
                short8 b = *reinterpret_cast<const short8*>(w2n + kk * 32);
                acc2[0][nt] = __builtin_amdgcn_mfma_f32_16x16x32_bf16(a2[0][kk], b, acc2[0][nt], 0, 0, 0);
                acc2[1][nt] = __builtin_amdgcn_mfma_f32_16x16x32_bf16(a2[1][kk], b, acc2[1][nt], 0, 0, 0);
            }
        }
        __syncthreads();
    }

    // epilogue: weighted atomic accumulate
#pragma unroll
    for (int mt = 0; mt < 2; mt++)
#pragma unroll
        for (int nt = 0; nt < 4; nt++) {
            int col = wave * 64 + nt * 16 + ln;
#pragma unroll
            for (int r = 0; r < 4; r++) {
                int m = mt * 16 + g * 4 + r;
                float val = acc2[mt][nt][r] * s_wgt[m];
                atomicAdd(out + s_tok[m] * DIM + col, val);
            }
        }
}

extern "C" void kernel_launch(void* const* d_in, const int* in_sizes, int n_in,
                              void* d_out, int out_size, void* d_ws, size_t ws_size,
                              hipStream_t stream) {
    const float* x  = (const float*)d_in[0];
    const float* wr = (const float*)d_in[1];
    const float* br = (const float*)d_in[2];
    const float* w1 = (const float*)d_in[3];
    const float* w2 = (const float*)d_in[4];
    float* out = (float*)d_out;
    float* logits_out = out + T_TOK * DIM;

    char* ws = (char*)d_ws;
    int*   counts = (int*)(ws + 0);
    int*   tlist  = (int*)(ws + 64);
    float* wlist  = (float*)(ws + 64 + 65536);
    unsigned short* xb  = (unsigned short*)(ws + 131328);            // 2 MB
    unsigned short* w1b = (unsigned short*)(ws + 2228480);           // 8 MB
    unsigned short* w2b = (unsigned short*)(ws + 10617088);          // 8 MB

    hipMemsetAsync(counts, 0, 64, stream);
    hipMemsetAsync(out, 0, T_TOK * DIM * sizeof(float), stream);

    cast_all<<<2304, 512, 0, stream>>>(w1, w2, x, w1b, w2b, xb);

    router_kernel<<<T_TOK / 4, 256, 0, stream>>>(x, wr, br, logits_out,
                                                 counts, tlist, wlist);

    moe_gemm<<<NE * 2 * (T_TOK / TM), 512, 0, stream>>>(xb, w1b, w2b,
                                                        counts, tlist, wlist, out);
}